// Round 1
// baseline (125.927 us; speedup 1.0000x reference)
//
#include <hip/hip_runtime.h>

// Problem constants
#define DIM 128
#define HID 256
#define K2LE 2.885390081777927f   // 2*log2(e): tanh(x) = 1 - 2/(exp2(K2LE*x)+1)
#define NTILES 16                 // HID / 16
#define RNPAD 136                 // rnbf row stride (bf16 elems)
#define GXPAD 260                 // g_x row stride (f32)

typedef __attribute__((ext_vector_type(8))) short bf16x8;   // 8 bf16 = 4 VGPRs
typedef __attribute__((ext_vector_type(4))) float f32x4;
typedef __attribute__((ext_vector_type(2))) float f32x2;    // -> v_pk_* f32

__device__ __forceinline__ unsigned short f2bf(float f) {
    union { float f; unsigned u; } x; x.f = f;
    unsigned r = x.u + 0x7fffu + ((x.u >> 16) & 1u);   // RNE
    return (unsigned short)(r >> 16);
}

__device__ __forceinline__ float sigmoid_fast(float x) {
    float t = __builtin_amdgcn_exp2f(-x * 1.4426950408889634f);
    return __builtin_amdgcn_rcpf(1.0f + t);
}

// All-reduce sum across a 16-lane DPP row — VALU pipe only, no LDS.
__device__ __forceinline__ float row16_allreduce(float x) {
    int t;
    t = __builtin_amdgcn_update_dpp(0, __float_as_int(x), 0xB1, 0xf, 0xf, true);
    x += __int_as_float(t);
    t = __builtin_amdgcn_update_dpp(0, __float_as_int(x), 0x4E, 0xf, 0xf, true);
    x += __int_as_float(t);
    t = __builtin_amdgcn_update_dpp(0, __float_as_int(x), 0x124, 0xf, 0xf, true);
    x += __int_as_float(t);
    t = __builtin_amdgcn_update_dpp(0, __float_as_int(x), 0x128, 0xf, 0xf, true);
    x += __int_as_float(t);
    return x;
}

// ---------------------------------------------------------------------------
// Prep (16 blocks x 256):
//   block 0: c2p/w2p[(col&15)*16 + (col>>4)] = K2LE*(pivot@W1+b1)[col], w2[col]
//   all:     W1f = bf16(K2LE*W1) in MFMA B-frag order
// ---------------------------------------------------------------------------
__global__ void k_prep(const float* __restrict__ pivot,
                       const float* __restrict__ W1,
                       const float* __restrict__ b1,
                       const float* __restrict__ w2,
                       float* __restrict__ c2p,
                       float* __restrict__ w2p,
                       uint4* __restrict__ W1f) {
    const int tid = threadIdx.x;
    if (blockIdx.x == 0) {
        float a = b1[tid];
#pragma unroll 8
        for (int d = 0; d < DIM; ++d) a = fmaf(pivot[d], W1[d * HID + tid], a);
        const int pidx = (tid & 15) * 16 + (tid >> 4);   // col -> [m][i]
        c2p[pidx] = K2LE * a;
        w2p[pidx] = w2[tid];
    }
    const int e  = blockIdx.x * 256 + tid;
    const int m  = e & 15;
    const int q  = (e >> 4) & 3;
    const int kk = (e >> 6) & 3;
    const int nt = e >> 8;
    const int n  = nt * 16 + m;
    const int k0 = kk * 32 + q * 8;
    unsigned w[4];
#pragma unroll
    for (int p = 0; p < 4; ++p) {
        unsigned lo = f2bf(W1[(k0 + 2 * p    ) * HID + n] * K2LE);
        unsigned hi = f2bf(W1[(k0 + 2 * p + 1) * HID + n] * K2LE);
        w[p] = lo | (hi << 16);
    }
    W1f[e] = make_uint4(w[0], w[1], w[2], w[3]);
}

// ---------------------------------------------------------------------------
// Fused main: 2048 blocks x 256 thr, 16 rays/block.
//  phase 1: lane(q,m) of wave w normalizes ray w*4+q; f32 dir kept in regs
//  phase 2: wave w MFMAs nt-group {4w..4w+3} for all 16 rays; D -> padded LDS
//  phase 3: quad-rcp sigmoid with f32x2 packed args (+v_pk_fma_f32 /
//           v_pk_add_f32); DPP row16 reduce
//  phase 4: epilogue from f32 regs (no LDS)
//
//  R12: rnbf (live phases 1-2) and g_x (live phases 2-3) ALIAS the same LDS
//  buffer, guarded by a barrier after the afrag register loads.  LDS/block
//  drops 20992 -> 16640 B, so all 8 blocks/CU (= the whole 2048-block grid)
//  are co-resident: kills the 256-block 1-block/CU tail that capped
//  occupancy at ~36%.
// ---------------------------------------------------------------------------
__global__ __launch_bounds__(256, 8) void k_main(
    const float* __restrict__ r,      // [B,128]
    const float* __restrict__ s,      // [B]
    const float* __restrict__ pivot,  // [128]
    const float* __restrict__ c2p,    // [256] permuted K2LE*(pivot@W1+b1)
    const float* __restrict__ w2p,    // [256] permuted w2
    const float* __restrict__ b2,     // [1]
    const int* __restrict__ n_iter_p, // [1]
    const uint4* __restrict__ W1f,    // frag-ordered bf16 K2LE*W1
    float* __restrict__ out)          // [B,128]
{
    // Aliased LDS: max(16*RNPAD*2, 16*GXPAD*4) = 16640 B
    __shared__ __align__(16) char smem[16 * GXPAD * 4];
    unsigned short (*rnbf)[RNPAD] = (unsigned short (*)[RNPAD])smem;  // [ray][k] bf16
    float          (*g_x)[GXPAD]  = (float (*)[GXPAD])smem;           // [ray][col] f32

    const int tid   = threadIdx.x;
    const int lane  = tid & 63;
    const int wave  = tid >> 6;        // 0..3: nt-group AND ray-group
    const int m     = lane & 15;
    const int q     = lane >> 4;
    const int ray_l = wave * 4 + q;    // this lane's ray (phases 1,3,4)
    const int ray_g = blockIdx.x * 16 + ray_l;
    const int n_iter = *n_iter_p;

    // ---- Phase 1: load r; keep f32 dir in regs; bf16 copy to LDS for MFMA ----
    float4 v0 = *(const float4*)&r[ray_g * DIM + m * 8];
    float4 v1 = *(const float4*)&r[ray_g * DIM + m * 8 + 4];
    const float sv  = s[ray_g];
    const float b2v = b2[0];

    float ss = v0.x*v0.x + v0.y*v0.y + v0.z*v0.z + v0.w*v0.w
             + v1.x*v1.x + v1.y*v1.y + v1.z*v1.z + v1.w*v1.w;
    ss = row16_allreduce(ss);
    const float inv = __builtin_amdgcn_rsqf(ss);
    unsigned p0 = (unsigned)f2bf(v0.x*inv) | ((unsigned)f2bf(v0.y*inv) << 16);
    unsigned p1 = (unsigned)f2bf(v0.z*inv) | ((unsigned)f2bf(v0.w*inv) << 16);
    unsigned p2 = (unsigned)f2bf(v1.x*inv) | ((unsigned)f2bf(v1.y*inv) << 16);
    unsigned p3 = (unsigned)f2bf(v1.z*inv) | ((unsigned)f2bf(v1.w*inv) << 16);
    *(uint4*)&rnbf[ray_l][m * 8] = make_uint4(p0, p1, p2, p3);
    __syncthreads();

    // ---- Phase 2: wave w computes nt = 4w..4w+3 for all 16 rays ----
    bf16x8 afrag[4];
#pragma unroll
    for (int kk = 0; kk < 4; ++kk)
        afrag[kk] = *(const bf16x8*)&rnbf[m][kk * 32 + q * 8];
    // rnbf is dead once afrag is in registers; barrier before g_x (same LDS)
    // is written below.
    __syncthreads();

    const bf16x8* __restrict__ wf = (const bf16x8*)W1f;
    const int fb = q * 16 + m;
#pragma unroll
    for (int t = 0; t < 4; ++t) {
        const int nt = wave * 4 + t;
        f32x4 a = {0.f, 0.f, 0.f, 0.f};
#pragma unroll
        for (int kk = 0; kk < 4; ++kk)
            a = __builtin_amdgcn_mfma_f32_16x16x32_bf16(
                    afrag[kk], wf[nt * 256 + kk * 64 + fb], a, 0, 0, 0);
        // D: row(ray) = q*4+reg, col = nt*16+m  (m89-verified layout)
#pragma unroll
        for (int r4 = 0; r4 < 4; ++r4)
            g_x[q * 4 + r4][nt * 16 + m] = a[r4];
    }
    __syncthreads();

    // ---- Phase 3 setup: lane's 16 cols {i*16+m}, packed into f32x2 pairs ----
    f32x2 g2[8], c2[8];
    float w[16];
#pragma unroll
    for (int j = 0; j < 8; ++j) {
        g2[j].x = g_x[ray_l][(2 * j    ) * 16 + m];
        g2[j].y = g_x[ray_l][(2 * j + 1) * 16 + m];
    }
#pragma unroll
    for (int i = 0; i < 4; ++i) {
        float4 cv = *(const float4*)(c2p + m * 16 + i * 4);
        float4 wv = *(const float4*)(w2p + m * 16 + i * 4);
        c2[2*i]   = (f32x2){cv.x, cv.y};
        c2[2*i+1] = (f32x2){cv.z, cv.w};
        w[4*i]=wv.x; w[4*i+1]=wv.y; w[4*i+2]=wv.z; w[4*i+3]=wv.w;
    }

    float S = 0.f;
#pragma unroll
    for (int i = 0; i < 16; ++i) S += w[i];
    S = row16_allreduce(S);
    const float C0 = K2LE * (S + b2v);

    // ---- Phase 3: march. Quad-rcp + packed args: one v_rcp per 4 sigmoids,
    //      arg compute and +1.0 as f32x2 (v_pk_fma_f32 / v_pk_add_f32). ----
    float alpha = 0.f;
    for (int it = 0; it < n_iter; ++it) {
        const f32x2 alpha2 = {alpha, alpha};
        float p = 0.f;
#pragma unroll
        for (int qd = 0; qd < 4; ++qd) {
            const int b = qd * 4;
            f32x2 arg01 = alpha2 * g2[2*qd]   + c2[2*qd];     // pk_fma
            f32x2 arg23 = alpha2 * g2[2*qd+1] + c2[2*qd+1];   // pk_fma
            f32x2 A01, A23;
            A01.x = __builtin_amdgcn_exp2f(arg01.x);
            A01.y = __builtin_amdgcn_exp2f(arg01.y);
            A23.x = __builtin_amdgcn_exp2f(arg23.x);
            A23.y = __builtin_amdgcn_exp2f(arg23.y);
            A01 += (f32x2){1.0f, 1.0f};                       // pk_add
            A23 += (f32x2){1.0f, 1.0f};                       // pk_add
            float P01 = A01.x * A01.y;
            float P23 = A23.x * A23.y;
            float n01 = fmaf(w[b+0], A01.y, w[b+1] * A01.x);
            float n23 = fmaf(w[b+2], A23.y, w[b+3] * A23.x);
            float num = fmaf(n01, P23, n23 * P01);
            float den = P01 * P23;
            p = fmaf(num, __builtin_amdgcn_rcpf(den), p);
        }
        p = row16_allreduce(p);
        float v = __builtin_amdgcn_rcpf(
            __builtin_amdgcn_exp2f(fmaf(-2.0f * K2LE, p, C0)) + 1.0f);
        alpha += fmaf(-0.1f, v, 0.1f);
    }

    // ---- Phase 4: out = pivot + sigmoid(s)*alpha*(r*inv) — all f32, no LDS ----
    const float sc = sigmoid_fast(sv) * alpha * inv;
    float4 pv0 = *(const float4*)(pivot + m * 8);
    float4 pv1 = *(const float4*)(pivot + m * 8 + 4);
    float4 o0, o1;
    o0.x = fmaf(sc, v0.x, pv0.x);
    o0.y = fmaf(sc, v0.y, pv0.y);
    o0.z = fmaf(sc, v0.z, pv0.z);
    o0.w = fmaf(sc, v0.w, pv0.w);
    o1.x = fmaf(sc, v1.x, pv1.x);
    o1.y = fmaf(sc, v1.y, pv1.y);
    o1.z = fmaf(sc, v1.z, pv1.z);
    o1.w = fmaf(sc, v1.w, pv1.w);
    *(float4*)(out + ray_g * DIM + m * 8)     = o0;
    *(float4*)(out + ray_g * DIM + m * 8 + 4) = o1;
}

extern "C" void kernel_launch(void* const* d_in, const int* in_sizes, int n_in,
                              void* d_out, int out_size, void* d_ws, size_t ws_size,
                              hipStream_t stream) {
    const float* r      = (const float*)d_in[0];
    const float* s      = (const float*)d_in[1];
    const float* pivot  = (const float*)d_in[2];
    const float* W1     = (const float*)d_in[3];
    const float* b1     = (const float*)d_in[4];
    const float* w2     = (const float*)d_in[5];
    const float* b2     = (const float*)d_in[6];
    const int*   n_iter = (const int*)d_in[7];
    float* out = (float*)d_out;

    const int B = in_sizes[0] / DIM;  // 32768

    char* ws = (char*)d_ws;
    float* c2p = (float*)(ws);             // 1 KB
    float* w2p = (float*)(ws + 1024);      // 1 KB
    uint4* W1f = (uint4*)(ws + 4096);      // 64 KB

    k_prep<<<16, 256, 0, stream>>>(pivot, W1, b1, w2, c2p, w2p, W1f);
    k_main<<<B / 16, 256, 0, stream>>>(r, s, pivot, c2p, w2p, b2, n_iter,
                                       W1f, out);
}

// Round 2
// 124.564 us; speedup vs baseline: 1.0109x; 1.0109x over previous
//
#include <hip/hip_runtime.h>

// Problem constants
#define DIM 128
#define HID 256
#define K2LE 2.885390081777927f   // 2*log2(e): tanh(x) = 1 - 2/(exp2(K2LE*x)+1)
#define NTILES 16                 // HID / 16
#define RNPAD 120                 // rnbf row stride (bf16): 240B = 15*16B, 16B-aligned rows
#define GXPAD 260                 // g_x row stride (f32)

typedef __attribute__((ext_vector_type(8))) short bf16x8;   // 8 bf16 = 4 VGPRs
typedef __attribute__((ext_vector_type(4))) float f32x4;
typedef __attribute__((ext_vector_type(2))) float f32x2;    // -> v_pk_* f32

__device__ __forceinline__ unsigned short f2bf(float f) {
    union { float f; unsigned u; } x; x.f = f;
    unsigned r = x.u + 0x7fffu + ((x.u >> 16) & 1u);   // RNE
    return (unsigned short)(r >> 16);
}

__device__ __forceinline__ float sigmoid_fast(float x) {
    float t = __builtin_amdgcn_exp2f(-x * 1.4426950408889634f);
    return __builtin_amdgcn_rcpf(1.0f + t);
}

// All-reduce sum across a 16-lane DPP row — VALU pipe only, no LDS.
__device__ __forceinline__ float row16_allreduce(float x) {
    int t;
    t = __builtin_amdgcn_update_dpp(0, __float_as_int(x), 0xB1, 0xf, 0xf, true);
    x += __int_as_float(t);
    t = __builtin_amdgcn_update_dpp(0, __float_as_int(x), 0x4E, 0xf, 0xf, true);
    x += __int_as_float(t);
    t = __builtin_amdgcn_update_dpp(0, __float_as_int(x), 0x124, 0xf, 0xf, true);
    x += __int_as_float(t);
    t = __builtin_amdgcn_update_dpp(0, __float_as_int(x), 0x128, 0xf, 0xf, true);
    x += __int_as_float(t);
    return x;
}

// ---------------------------------------------------------------------------
// Prep (16 blocks x 256):
//   block 0: c2p/w2p[(col&15)*16 + (col>>4)] = K2LE*(pivot@W1+b1)[col], w2[col]
//   all:     W1f = bf16(K2LE*W1) in MFMA B-frag order
// ---------------------------------------------------------------------------
__global__ void k_prep(const float* __restrict__ pivot,
                       const float* __restrict__ W1,
                       const float* __restrict__ b1,
                       const float* __restrict__ w2,
                       float* __restrict__ c2p,
                       float* __restrict__ w2p,
                       uint4* __restrict__ W1f) {
    const int tid = threadIdx.x;
    if (blockIdx.x == 0) {
        float a = b1[tid];
#pragma unroll 8
        for (int d = 0; d < DIM; ++d) a = fmaf(pivot[d], W1[d * HID + tid], a);
        const int pidx = (tid & 15) * 16 + (tid >> 4);   // col -> [m][i]
        c2p[pidx] = K2LE * a;
        w2p[pidx] = w2[tid];
    }
    const int e  = blockIdx.x * 256 + tid;
    const int m  = e & 15;
    const int q  = (e >> 4) & 3;
    const int kk = (e >> 6) & 3;
    const int nt = e >> 8;
    const int n  = nt * 16 + m;
    const int k0 = kk * 32 + q * 8;
    unsigned w[4];
#pragma unroll
    for (int p = 0; p < 4; ++p) {
        unsigned lo = f2bf(W1[(k0 + 2 * p    ) * HID + n] * K2LE);
        unsigned hi = f2bf(W1[(k0 + 2 * p + 1) * HID + n] * K2LE);
        w[p] = lo | (hi << 16);
    }
    W1f[e] = make_uint4(w[0], w[1], w[2], w[3]);
}

// ---------------------------------------------------------------------------
// Fused main: 2048 blocks x 256 thr, 16 rays/block.  (R0 structure)
//  R13: (a) RNPAD 136->120: LDS total = 3840 + 16640 = 20480 B exactly ->
//       8 blocks/CU with SEPARATE shared arrays (R1's aliasing pessimized
//       codegen: VGPR 44->32, +idle).  Rows stay 16B-aligned (240 = 15*16).
//       (b) per-block s_sleep skew (0..448 cyc) at entry: waves on a SIMD
//       come from different blocks; skewing blocks decorrelates the serial
//       DPP-allreduce / sigmoid-tail stalls that phase-locked waves hit
//       simultaneously (R0/R1: ~40% idle at 58-62% VALUBusy).
// ---------------------------------------------------------------------------
__global__ __launch_bounds__(256, 8) void k_main(
    const float* __restrict__ r,      // [B,128]
    const float* __restrict__ s,      // [B]
    const float* __restrict__ pivot,  // [128]
    const float* __restrict__ c2p,    // [256] permuted K2LE*(pivot@W1+b1)
    const float* __restrict__ w2p,    // [256] permuted w2
    const float* __restrict__ b2,     // [1]
    const int* __restrict__ n_iter_p, // [1]
    const uint4* __restrict__ W1f,    // frag-ordered bf16 K2LE*W1
    float* __restrict__ out)          // [B,128]
{
    __shared__ unsigned short rnbf[16][RNPAD];  // 3.75 KB [ray][k] bf16, padded
    __shared__ float g_x[16][GXPAD];            // 16.25 KB [ray][col] f32, padded

    // Desync blocks (and thus the waves sharing each SIMD): 0..7 * 64 cycles.
    {
        const unsigned skew = blockIdx.x & 7u;
        if (skew & 1u) __builtin_amdgcn_s_sleep(1);
        if (skew & 2u) __builtin_amdgcn_s_sleep(2);
        if (skew & 4u) __builtin_amdgcn_s_sleep(4);
    }

    const int tid   = threadIdx.x;
    const int lane  = tid & 63;
    const int wave  = tid >> 6;        // 0..3: nt-group AND ray-group
    const int m     = lane & 15;
    const int q     = lane >> 4;
    const int ray_l = wave * 4 + q;    // this lane's ray (phases 1,3,4)
    const int ray_g = blockIdx.x * 16 + ray_l;
    const int n_iter = *n_iter_p;

    // ---- Phase 1: load r; keep f32 dir in regs; bf16 copy to LDS for MFMA ----
    float4 v0 = *(const float4*)&r[ray_g * DIM + m * 8];
    float4 v1 = *(const float4*)&r[ray_g * DIM + m * 8 + 4];
    const float sv  = s[ray_g];
    const float b2v = b2[0];

    float ss = v0.x*v0.x + v0.y*v0.y + v0.z*v0.z + v0.w*v0.w
             + v1.x*v1.x + v1.y*v1.y + v1.z*v1.z + v1.w*v1.w;
    ss = row16_allreduce(ss);
    const float inv = __builtin_amdgcn_rsqf(ss);
    unsigned p0 = (unsigned)f2bf(v0.x*inv) | ((unsigned)f2bf(v0.y*inv) << 16);
    unsigned p1 = (unsigned)f2bf(v0.z*inv) | ((unsigned)f2bf(v0.w*inv) << 16);
    unsigned p2 = (unsigned)f2bf(v1.x*inv) | ((unsigned)f2bf(v1.y*inv) << 16);
    unsigned p3 = (unsigned)f2bf(v1.z*inv) | ((unsigned)f2bf(v1.w*inv) << 16);
    *(uint4*)&rnbf[ray_l][m * 8] = make_uint4(p0, p1, p2, p3);
    __syncthreads();

    // ---- Phase 2: wave w computes nt = 4w..4w+3 for all 16 rays ----
    bf16x8 afrag[4];
#pragma unroll
    for (int kk = 0; kk < 4; ++kk)
        afrag[kk] = *(const bf16x8*)&rnbf[m][kk * 32 + q * 8];

    const bf16x8* __restrict__ wf = (const bf16x8*)W1f;
    const int fb = q * 16 + m;
#pragma unroll
    for (int t = 0; t < 4; ++t) {
        const int nt = wave * 4 + t;
        f32x4 a = {0.f, 0.f, 0.f, 0.f};
#pragma unroll
        for (int kk = 0; kk < 4; ++kk)
            a = __builtin_amdgcn_mfma_f32_16x16x32_bf16(
                    afrag[kk], wf[nt * 256 + kk * 64 + fb], a, 0, 0, 0);
        // D: row(ray) = q*4+reg, col = nt*16+m  (m89-verified layout)
#pragma unroll
        for (int r4 = 0; r4 < 4; ++r4)
            g_x[q * 4 + r4][nt * 16 + m] = a[r4];
    }
    __syncthreads();

    // ---- Phase 3 setup: lane's 16 cols {i*16+m}, packed into f32x2 pairs ----
    f32x2 g2[8], c2[8];
    float w[16];
#pragma unroll
    for (int j = 0; j < 8; ++j) {
        g2[j].x = g_x[ray_l][(2 * j    ) * 16 + m];
        g2[j].y = g_x[ray_l][(2 * j + 1) * 16 + m];
    }
#pragma unroll
    for (int i = 0; i < 4; ++i) {
        float4 cv = *(const float4*)(c2p + m * 16 + i * 4);
        float4 wv = *(const float4*)(w2p + m * 16 + i * 4);
        c2[2*i]   = (f32x2){cv.x, cv.y};
        c2[2*i+1] = (f32x2){cv.z, cv.w};
        w[4*i]=wv.x; w[4*i+1]=wv.y; w[4*i+2]=wv.z; w[4*i+3]=wv.w;
    }

    float S = 0.f;
#pragma unroll
    for (int i = 0; i < 16; ++i) S += w[i];
    S = row16_allreduce(S);
    const float C0 = K2LE * (S + b2v);

    // ---- Phase 3: march. Quad-rcp + packed args: one v_rcp per 4 sigmoids,
    //      arg compute and +1.0 as f32x2 (v_pk_fma_f32 / v_pk_add_f32). ----
    float alpha = 0.f;
    for (int it = 0; it < n_iter; ++it) {
        const f32x2 alpha2 = {alpha, alpha};
        float p = 0.f;
#pragma unroll
        for (int qd = 0; qd < 4; ++qd) {
            const int b = qd * 4;
            f32x2 arg01 = alpha2 * g2[2*qd]   + c2[2*qd];     // pk_fma
            f32x2 arg23 = alpha2 * g2[2*qd+1] + c2[2*qd+1];   // pk_fma
            f32x2 A01, A23;
            A01.x = __builtin_amdgcn_exp2f(arg01.x);
            A01.y = __builtin_amdgcn_exp2f(arg01.y);
            A23.x = __builtin_amdgcn_exp2f(arg23.x);
            A23.y = __builtin_amdgcn_exp2f(arg23.y);
            A01 += (f32x2){1.0f, 1.0f};                       // pk_add
            A23 += (f32x2){1.0f, 1.0f};                       // pk_add
            float P01 = A01.x * A01.y;
            float P23 = A23.x * A23.y;
            float n01 = fmaf(w[b+0], A01.y, w[b+1] * A01.x);
            float n23 = fmaf(w[b+2], A23.y, w[b+3] * A23.x);
            float num = fmaf(n01, P23, n23 * P01);
            float den = P01 * P23;
            p = fmaf(num, __builtin_amdgcn_rcpf(den), p);
        }
        p = row16_allreduce(p);
        float v = __builtin_amdgcn_rcpf(
            __builtin_amdgcn_exp2f(fmaf(-2.0f * K2LE, p, C0)) + 1.0f);
        alpha += fmaf(-0.1f, v, 0.1f);
    }

    // ---- Phase 4: out = pivot + sigmoid(s)*alpha*(r*inv) — all f32, no LDS ----
    const float sc = sigmoid_fast(sv) * alpha * inv;
    float4 pv0 = *(const float4*)(pivot + m * 8);
    float4 pv1 = *(const float4*)(pivot + m * 8 + 4);
    float4 o0, o1;
    o0.x = fmaf(sc, v0.x, pv0.x);
    o0.y = fmaf(sc, v0.y, pv0.y);
    o0.z = fmaf(sc, v0.z, pv0.z);
    o0.w = fmaf(sc, v0.w, pv0.w);
    o1.x = fmaf(sc, v1.x, pv1.x);
    o1.y = fmaf(sc, v1.y, pv1.y);
    o1.z = fmaf(sc, v1.z, pv1.z);
    o1.w = fmaf(sc, v1.w, pv1.w);
    *(float4*)(out + ray_g * DIM + m * 8)     = o0;
    *(float4*)(out + ray_g * DIM + m * 8 + 4) = o1;
}

extern "C" void kernel_launch(void* const* d_in, const int* in_sizes, int n_in,
                              void* d_out, int out_size, void* d_ws, size_t ws_size,
                              hipStream_t stream) {
    const float* r      = (const float*)d_in[0];
    const float* s      = (const float*)d_in[1];
    const float* pivot  = (const float*)d_in[2];
    const float* W1     = (const float*)d_in[3];
    const float* b1     = (const float*)d_in[4];
    const float* w2     = (const float*)d_in[5];
    const float* b2     = (const float*)d_in[6];
    const int*   n_iter = (const int*)d_in[7];
    float* out = (float*)d_out;

    const int B = in_sizes[0] / DIM;  // 32768

    char* ws = (char*)d_ws;
    float* c2p = (float*)(ws);             // 1 KB
    float* w2p = (float*)(ws + 1024);      // 1 KB
    uint4* W1f = (uint4*)(ws + 4096);      // 64 KB

    k_prep<<<16, 256, 0, stream>>>(pivot, W1, b1, w2, c2p, w2p, W1f);
    k_main<<<B / 16, 256, 0, stream>>>(r, s, pivot, c2p, w2p, b2, n_iter,
                                       W1f, out);
}

// Round 3
// 122.065 us; speedup vs baseline: 1.0316x; 1.0205x over previous
//
#include <hip/hip_runtime.h>

// Problem constants
#define DIM 128
#define HID 256
#define K2LE 2.885390081777927f   // 2*log2(e): tanh(x) = 1 - 2/(exp2(K2LE*x)+1)
#define NTILES 16                 // HID / 16
#define RNPAD 136                 // rnbf row stride (bf16 elems)
#define GXPAD 260                 // g_x row stride (f32)

typedef __attribute__((ext_vector_type(8))) short bf16x8;   // 8 bf16 = 4 VGPRs
typedef __attribute__((ext_vector_type(4))) float f32x4;
typedef __attribute__((ext_vector_type(2))) float f32x2;    // -> v_pk_* f32

__device__ __forceinline__ unsigned short f2bf(float f) {
    union { float f; unsigned u; } x; x.f = f;
    unsigned r = x.u + 0x7fffu + ((x.u >> 16) & 1u);   // RNE
    return (unsigned short)(r >> 16);
}

__device__ __forceinline__ float sigmoid_fast(float x) {
    float t = __builtin_amdgcn_exp2f(-x * 1.4426950408889634f);
    return __builtin_amdgcn_rcpf(1.0f + t);
}

// All-reduce sum across a 16-lane DPP row — VALU pipe only, no LDS.
__device__ __forceinline__ float row16_allreduce(float x) {
    int t;
    t = __builtin_amdgcn_update_dpp(0, __float_as_int(x), 0xB1, 0xf, 0xf, true);
    x += __int_as_float(t);
    t = __builtin_amdgcn_update_dpp(0, __float_as_int(x), 0x4E, 0xf, 0xf, true);
    x += __int_as_float(t);
    t = __builtin_amdgcn_update_dpp(0, __float_as_int(x), 0x124, 0xf, 0xf, true);
    x += __int_as_float(t);
    t = __builtin_amdgcn_update_dpp(0, __float_as_int(x), 0x128, 0xf, 0xf, true);
    x += __int_as_float(t);
    return x;
}

// ---------------------------------------------------------------------------
// Prep (16 blocks x 256):
//   block 0: c2p/w2p[(col&15)*16 + (col>>4)] = K2LE*(pivot@W1+b1)[col], w2[col]
//   all:     W1f = bf16(K2LE*W1) in MFMA B-frag order
// ---------------------------------------------------------------------------
__global__ void k_prep(const float* __restrict__ pivot,
                       const float* __restrict__ W1,
                       const float* __restrict__ b1,
                       const float* __restrict__ w2,
                       float* __restrict__ c2p,
                       float* __restrict__ w2p,
                       uint4* __restrict__ W1f) {
    const int tid = threadIdx.x;
    if (blockIdx.x == 0) {
        float a = b1[tid];
#pragma unroll 8
        for (int d = 0; d < DIM; ++d) a = fmaf(pivot[d], W1[d * HID + tid], a);
        const int pidx = (tid & 15) * 16 + (tid >> 4);   // col -> [m][i]
        c2p[pidx] = K2LE * a;
        w2p[pidx] = w2[tid];
    }
    const int e  = blockIdx.x * 256 + tid;
    const int m  = e & 15;
    const int q  = (e >> 4) & 3;
    const int kk = (e >> 6) & 3;
    const int nt = e >> 8;
    const int n  = nt * 16 + m;
    const int k0 = kk * 32 + q * 8;
    unsigned w[4];
#pragma unroll
    for (int p = 0; p < 4; ++p) {
        unsigned lo = f2bf(W1[(k0 + 2 * p    ) * HID + n] * K2LE);
        unsigned hi = f2bf(W1[(k0 + 2 * p + 1) * HID + n] * K2LE);
        w[p] = lo | (hi << 16);
    }
    W1f[e] = make_uint4(w[0], w[1], w[2], w[3]);
}

// ---------------------------------------------------------------------------
// Fused main: 2048 blocks x 256 thr, 16 rays/block.  (exact R0 structure)
//  R14: register-pressure relief, math bit-identical to R0:
//   (a) __launch_bounds__(256,7): LDS (20992B) caps residency at 7 blocks/CU
//       anyway, so the (256,8) VGPR cap of 64 bought nothing while forcing
//       the ~60 live march-loop values (g2/c2/w = 48 floats + dirs + state)
//       into AGPR shuffles / remat each iteration.  Budget 64 -> 73.
//   (b) v0/v1 are NOT held across the march: phase 4 re-loads them from r
//       (read-only, cached) — frees 8 VGPRs across the 20-iter loop.
//  R1/R2 lesson: aliasing smem or inserting entry-skew flipped the compiler
//  into a 32-VGPR scratch-spilling schedule (WRITE_SIZE 16->45 MB).  Keep
//  the R0 source shape everywhere else.
// ---------------------------------------------------------------------------
__global__ __launch_bounds__(256, 7) void k_main(
    const float* __restrict__ r,      // [B,128]
    const float* __restrict__ s,      // [B]
    const float* __restrict__ pivot,  // [128]
    const float* __restrict__ c2p,    // [256] permuted K2LE*(pivot@W1+b1)
    const float* __restrict__ w2p,    // [256] permuted w2
    const float* __restrict__ b2,     // [1]
    const int* __restrict__ n_iter_p, // [1]
    const uint4* __restrict__ W1f,    // frag-ordered bf16 K2LE*W1
    float* __restrict__ out)          // [B,128]
{
    __shared__ unsigned short rnbf[16][RNPAD];  // 4.25 KB [ray][k] bf16, padded
    __shared__ float g_x[16][GXPAD];            // 16.25 KB [ray][col] f32, padded

    const int tid   = threadIdx.x;
    const int lane  = tid & 63;
    const int wave  = tid >> 6;        // 0..3: nt-group AND ray-group
    const int m     = lane & 15;
    const int q     = lane >> 4;
    const int ray_l = wave * 4 + q;    // this lane's ray (phases 1,3,4)
    const int ray_g = blockIdx.x * 16 + ray_l;
    const int n_iter = *n_iter_p;

    // ---- Phase 1: load r; bf16 copy to LDS for MFMA; dirs NOT kept live ----
    float4 v0 = *(const float4*)&r[ray_g * DIM + m * 8];
    float4 v1 = *(const float4*)&r[ray_g * DIM + m * 8 + 4];
    const float sv  = s[ray_g];
    const float b2v = b2[0];

    float ss = v0.x*v0.x + v0.y*v0.y + v0.z*v0.z + v0.w*v0.w
             + v1.x*v1.x + v1.y*v1.y + v1.z*v1.z + v1.w*v1.w;
    ss = row16_allreduce(ss);
    const float inv = __builtin_amdgcn_rsqf(ss);
    unsigned p0 = (unsigned)f2bf(v0.x*inv) | ((unsigned)f2bf(v0.y*inv) << 16);
    unsigned p1 = (unsigned)f2bf(v0.z*inv) | ((unsigned)f2bf(v0.w*inv) << 16);
    unsigned p2 = (unsigned)f2bf(v1.x*inv) | ((unsigned)f2bf(v1.y*inv) << 16);
    unsigned p3 = (unsigned)f2bf(v1.z*inv) | ((unsigned)f2bf(v1.w*inv) << 16);
    *(uint4*)&rnbf[ray_l][m * 8] = make_uint4(p0, p1, p2, p3);
    __syncthreads();

    // ---- Phase 2: wave w computes nt = 4w..4w+3 for all 16 rays ----
    bf16x8 afrag[4];
#pragma unroll
    for (int kk = 0; kk < 4; ++kk)
        afrag[kk] = *(const bf16x8*)&rnbf[m][kk * 32 + q * 8];

    const bf16x8* __restrict__ wf = (const bf16x8*)W1f;
    const int fb = q * 16 + m;
#pragma unroll
    for (int t = 0; t < 4; ++t) {
        const int nt = wave * 4 + t;
        f32x4 a = {0.f, 0.f, 0.f, 0.f};
#pragma unroll
        for (int kk = 0; kk < 4; ++kk)
            a = __builtin_amdgcn_mfma_f32_16x16x32_bf16(
                    afrag[kk], wf[nt * 256 + kk * 64 + fb], a, 0, 0, 0);
        // D: row(ray) = q*4+reg, col = nt*16+m  (m89-verified layout)
#pragma unroll
        for (int r4 = 0; r4 < 4; ++r4)
            g_x[q * 4 + r4][nt * 16 + m] = a[r4];
    }
    __syncthreads();

    // ---- Phase 3 setup: lane's 16 cols {i*16+m}, packed into f32x2 pairs ----
    f32x2 g2[8], c2[8];
    float w[16];
#pragma unroll
    for (int j = 0; j < 8; ++j) {
        g2[j].x = g_x[ray_l][(2 * j    ) * 16 + m];
        g2[j].y = g_x[ray_l][(2 * j + 1) * 16 + m];
    }
#pragma unroll
    for (int i = 0; i < 4; ++i) {
        float4 cv = *(const float4*)(c2p + m * 16 + i * 4);
        float4 wv = *(const float4*)(w2p + m * 16 + i * 4);
        c2[2*i]   = (f32x2){cv.x, cv.y};
        c2[2*i+1] = (f32x2){cv.z, cv.w};
        w[4*i]=wv.x; w[4*i+1]=wv.y; w[4*i+2]=wv.z; w[4*i+3]=wv.w;
    }

    float S = 0.f;
#pragma unroll
    for (int i = 0; i < 16; ++i) S += w[i];
    S = row16_allreduce(S);
    const float C0 = K2LE * (S + b2v);

    // ---- Phase 3: march. Quad-rcp + packed args: one v_rcp per 4 sigmoids,
    //      arg compute and +1.0 as f32x2 (v_pk_fma_f32 / v_pk_add_f32). ----
    float alpha = 0.f;
    for (int it = 0; it < n_iter; ++it) {
        const f32x2 alpha2 = {alpha, alpha};
        float p = 0.f;
#pragma unroll
        for (int qd = 0; qd < 4; ++qd) {
            const int b = qd * 4;
            f32x2 arg01 = alpha2 * g2[2*qd]   + c2[2*qd];     // pk_fma
            f32x2 arg23 = alpha2 * g2[2*qd+1] + c2[2*qd+1];   // pk_fma
            f32x2 A01, A23;
            A01.x = __builtin_amdgcn_exp2f(arg01.x);
            A01.y = __builtin_amdgcn_exp2f(arg01.y);
            A23.x = __builtin_amdgcn_exp2f(arg23.x);
            A23.y = __builtin_amdgcn_exp2f(arg23.y);
            A01 += (f32x2){1.0f, 1.0f};                       // pk_add
            A23 += (f32x2){1.0f, 1.0f};                       // pk_add
            float P01 = A01.x * A01.y;
            float P23 = A23.x * A23.y;
            float n01 = fmaf(w[b+0], A01.y, w[b+1] * A01.x);
            float n23 = fmaf(w[b+2], A23.y, w[b+3] * A23.x);
            float num = fmaf(n01, P23, n23 * P01);
            float den = P01 * P23;
            p = fmaf(num, __builtin_amdgcn_rcpf(den), p);
        }
        p = row16_allreduce(p);
        float v = __builtin_amdgcn_rcpf(
            __builtin_amdgcn_exp2f(fmaf(-2.0f * K2LE, p, C0)) + 1.0f);
        alpha += fmaf(-0.1f, v, 0.1f);
    }

    // ---- Phase 4: out = pivot + sigmoid(s)*alpha*(r*inv).  Dirs re-loaded
    //      from r (bit-identical values; r is unmodified and L2/L3-hot) ----
    const float sc = sigmoid_fast(sv) * alpha * inv;
    float4 u0 = *(const float4*)&r[ray_g * DIM + m * 8];
    float4 u1 = *(const float4*)&r[ray_g * DIM + m * 8 + 4];
    float4 pv0 = *(const float4*)(pivot + m * 8);
    float4 pv1 = *(const float4*)(pivot + m * 8 + 4);
    float4 o0, o1;
    o0.x = fmaf(sc, u0.x, pv0.x);
    o0.y = fmaf(sc, u0.y, pv0.y);
    o0.z = fmaf(sc, u0.z, pv0.z);
    o0.w = fmaf(sc, u0.w, pv0.w);
    o1.x = fmaf(sc, u1.x, pv1.x);
    o1.y = fmaf(sc, u1.y, pv1.y);
    o1.z = fmaf(sc, u1.z, pv1.z);
    o1.w = fmaf(sc, u1.w, pv1.w);
    *(float4*)(out + ray_g * DIM + m * 8)     = o0;
    *(float4*)(out + ray_g * DIM + m * 8 + 4) = o1;
}

extern "C" void kernel_launch(void* const* d_in, const int* in_sizes, int n_in,
                              void* d_out, int out_size, void* d_ws, size_t ws_size,
                              hipStream_t stream) {
    const float* r      = (const float*)d_in[0];
    const float* s      = (const float*)d_in[1];
    const float* pivot  = (const float*)d_in[2];
    const float* W1     = (const float*)d_in[3];
    const float* b1     = (const float*)d_in[4];
    const float* w2     = (const float*)d_in[5];
    const float* b2     = (const float*)d_in[6];
    const int*   n_iter = (const int*)d_in[7];
    float* out = (float*)d_out;

    const int B = in_sizes[0] / DIM;  // 32768

    char* ws = (char*)d_ws;
    float* c2p = (float*)(ws);             // 1 KB
    float* w2p = (float*)(ws + 1024);      // 1 KB
    uint4* W1f = (uint4*)(ws + 4096);      // 64 KB

    k_prep<<<16, 256, 0, stream>>>(pivot, W1, b1, w2, c2p, w2p, W1f);
    k_main<<<B / 16, 256, 0, stream>>>(r, s, pivot, c2p, w2p, b2, n_iter,
                                       W1f, out);
}

// Round 4
// 120.914 us; speedup vs baseline: 1.0415x; 1.0095x over previous
//
#include <hip/hip_runtime.h>

// Problem constants
#define DIM 128
#define HID 256
#define K2LE 2.885390081777927f   // 2*log2(e): tanh(x) = 1 - 2/(exp2(K2LE*x)+1)
#define NTILES 16                 // HID / 16
#define RNPAD 120                 // rnbf row stride (bf16): 240B = 15*16B, rows 16B-aligned
#define GXPAD 260                 // g_x row stride (f32)

typedef __attribute__((ext_vector_type(8))) short bf16x8;   // 8 bf16 = 4 VGPRs
typedef __attribute__((ext_vector_type(4))) float f32x4;
typedef __attribute__((ext_vector_type(2))) float f32x2;    // -> v_pk_* f32

__device__ __forceinline__ unsigned short f2bf(float f) {
    union { float f; unsigned u; } x; x.f = f;
    unsigned r = x.u + 0x7fffu + ((x.u >> 16) & 1u);   // RNE
    return (unsigned short)(r >> 16);
}

__device__ __forceinline__ float sigmoid_fast(float x) {
    float t = __builtin_amdgcn_exp2f(-x * 1.4426950408889634f);
    return __builtin_amdgcn_rcpf(1.0f + t);
}

// All-reduce sum across a 16-lane DPP row — VALU pipe only, no LDS.
__device__ __forceinline__ float row16_allreduce(float x) {
    int t;
    t = __builtin_amdgcn_update_dpp(0, __float_as_int(x), 0xB1, 0xf, 0xf, true);
    x += __int_as_float(t);
    t = __builtin_amdgcn_update_dpp(0, __float_as_int(x), 0x4E, 0xf, 0xf, true);
    x += __int_as_float(t);
    t = __builtin_amdgcn_update_dpp(0, __float_as_int(x), 0x124, 0xf, 0xf, true);
    x += __int_as_float(t);
    t = __builtin_amdgcn_update_dpp(0, __float_as_int(x), 0x128, 0xf, 0xf, true);
    x += __int_as_float(t);
    return x;
}

// ---------------------------------------------------------------------------
// Prep (16 blocks x 256):
//   block 0: c2p/w2p[(col&15)*16 + (col>>4)] = K2LE*(pivot@W1+b1)[col], w2[col]
//   all:     W1f = bf16(K2LE*W1) in MFMA B-frag order
// ---------------------------------------------------------------------------
__global__ void k_prep(const float* __restrict__ pivot,
                       const float* __restrict__ W1,
                       const float* __restrict__ b1,
                       const float* __restrict__ w2,
                       float* __restrict__ c2p,
                       float* __restrict__ w2p,
                       uint4* __restrict__ W1f) {
    const int tid = threadIdx.x;
    if (blockIdx.x == 0) {
        float a = b1[tid];
#pragma unroll 8
        for (int d = 0; d < DIM; ++d) a = fmaf(pivot[d], W1[d * HID + tid], a);
        const int pidx = (tid & 15) * 16 + (tid >> 4);   // col -> [m][i]
        c2p[pidx] = K2LE * a;
        w2p[pidx] = w2[tid];
    }
    const int e  = blockIdx.x * 256 + tid;
    const int m  = e & 15;
    const int q  = (e >> 4) & 3;
    const int kk = (e >> 6) & 3;
    const int nt = e >> 8;
    const int n  = nt * 16 + m;
    const int k0 = kk * 32 + q * 8;
    unsigned w[4];
#pragma unroll
    for (int p = 0; p < 4; ++p) {
        unsigned lo = f2bf(W1[(k0 + 2 * p    ) * HID + n] * K2LE);
        unsigned hi = f2bf(W1[(k0 + 2 * p + 1) * HID + n] * K2LE);
        w[p] = lo | (hi << 16);
    }
    W1f[e] = make_uint4(w[0], w[1], w[2], w[3]);
}

// ---------------------------------------------------------------------------
// Fused main: 2048 blocks x 256 thr, 16 rays/block.  (exact R3 structure)
//  R15: RNPAD 136->120 ONLY.  LDS = 3840 + 16640 = 20480 B -> 8 blocks/CU
//  (8 x 20480 = 160 KiB exactly).  Grid is exactly 8 blocks/CU, so at 7
//  resident the 8th block per CU ran as a near-solo second generation:
//  wall ~= 2x block-time at ~57% utilization (matches the stuck 58-64%
//  VALUBusy of R0-R3).  One co-resident generation removes it.
//  R1/R2 lesson: smem aliasing / entry-skew flipped codegen into a
//  32-VGPR spill schedule (WRITE 16->45MB); this diff touches neither.
//  Guard counters: VGPR~36 SGPR~96 WRITE_SIZE=16384KB, else revert.
// ---------------------------------------------------------------------------
__global__ __launch_bounds__(256, 7) void k_main(
    const float* __restrict__ r,      // [B,128]
    const float* __restrict__ s,      // [B]
    const float* __restrict__ pivot,  // [128]
    const float* __restrict__ c2p,    // [256] permuted K2LE*(pivot@W1+b1)
    const float* __restrict__ w2p,    // [256] permuted w2
    const float* __restrict__ b2,     // [1]
    const int* __restrict__ n_iter_p, // [1]
    const uint4* __restrict__ W1f,    // frag-ordered bf16 K2LE*W1
    float* __restrict__ out)          // [B,128]
{
    __shared__ unsigned short rnbf[16][RNPAD];  // 3.75 KB [ray][k] bf16, padded
    __shared__ float g_x[16][GXPAD];            // 16.25 KB [ray][col] f32, padded

    const int tid   = threadIdx.x;
    const int lane  = tid & 63;
    const int wave  = tid >> 6;        // 0..3: nt-group AND ray-group
    const int m     = lane & 15;
    const int q     = lane >> 4;
    const int ray_l = wave * 4 + q;    // this lane's ray (phases 1,3,4)
    const int ray_g = blockIdx.x * 16 + ray_l;
    const int n_iter = *n_iter_p;

    // ---- Phase 1: load r; bf16 copy to LDS for MFMA; dirs NOT kept live ----
    float4 v0 = *(const float4*)&r[ray_g * DIM + m * 8];
    float4 v1 = *(const float4*)&r[ray_g * DIM + m * 8 + 4];
    const float sv  = s[ray_g];
    const float b2v = b2[0];

    float ss = v0.x*v0.x + v0.y*v0.y + v0.z*v0.z + v0.w*v0.w
             + v1.x*v1.x + v1.y*v1.y + v1.z*v1.z + v1.w*v1.w;
    ss = row16_allreduce(ss);
    const float inv = __builtin_amdgcn_rsqf(ss);
    unsigned p0 = (unsigned)f2bf(v0.x*inv) | ((unsigned)f2bf(v0.y*inv) << 16);
    unsigned p1 = (unsigned)f2bf(v0.z*inv) | ((unsigned)f2bf(v0.w*inv) << 16);
    unsigned p2 = (unsigned)f2bf(v1.x*inv) | ((unsigned)f2bf(v1.y*inv) << 16);
    unsigned p3 = (unsigned)f2bf(v1.z*inv) | ((unsigned)f2bf(v1.w*inv) << 16);
    *(uint4*)&rnbf[ray_l][m * 8] = make_uint4(p0, p1, p2, p3);
    __syncthreads();

    // ---- Phase 2: wave w computes nt = 4w..4w+3 for all 16 rays ----
    bf16x8 afrag[4];
#pragma unroll
    for (int kk = 0; kk < 4; ++kk)
        afrag[kk] = *(const bf16x8*)&rnbf[m][kk * 32 + q * 8];

    const bf16x8* __restrict__ wf = (const bf16x8*)W1f;
    const int fb = q * 16 + m;
#pragma unroll
    for (int t = 0; t < 4; ++t) {
        const int nt = wave * 4 + t;
        f32x4 a = {0.f, 0.f, 0.f, 0.f};
#pragma unroll
        for (int kk = 0; kk < 4; ++kk)
            a = __builtin_amdgcn_mfma_f32_16x16x32_bf16(
                    afrag[kk], wf[nt * 256 + kk * 64 + fb], a, 0, 0, 0);
        // D: row(ray) = q*4+reg, col = nt*16+m  (m89-verified layout)
#pragma unroll
        for (int r4 = 0; r4 < 4; ++r4)
            g_x[q * 4 + r4][nt * 16 + m] = a[r4];
    }
    __syncthreads();

    // ---- Phase 3 setup: lane's 16 cols {i*16+m}, packed into f32x2 pairs ----
    f32x2 g2[8], c2[8];
    float w[16];
#pragma unroll
    for (int j = 0; j < 8; ++j) {
        g2[j].x = g_x[ray_l][(2 * j    ) * 16 + m];
        g2[j].y = g_x[ray_l][(2 * j + 1) * 16 + m];
    }
#pragma unroll
    for (int i = 0; i < 4; ++i) {
        float4 cv = *(const float4*)(c2p + m * 16 + i * 4);
        float4 wv = *(const float4*)(w2p + m * 16 + i * 4);
        c2[2*i]   = (f32x2){cv.x, cv.y};
        c2[2*i+1] = (f32x2){cv.z, cv.w};
        w[4*i]=wv.x; w[4*i+1]=wv.y; w[4*i+2]=wv.z; w[4*i+3]=wv.w;
    }

    float S = 0.f;
#pragma unroll
    for (int i = 0; i < 16; ++i) S += w[i];
    S = row16_allreduce(S);
    const float C0 = K2LE * (S + b2v);

    // ---- Phase 3: march. Quad-rcp + packed args: one v_rcp per 4 sigmoids,
    //      arg compute and +1.0 as f32x2 (v_pk_fma_f32 / v_pk_add_f32). ----
    float alpha = 0.f;
    for (int it = 0; it < n_iter; ++it) {
        const f32x2 alpha2 = {alpha, alpha};
        float p = 0.f;
#pragma unroll
        for (int qd = 0; qd < 4; ++qd) {
            const int b = qd * 4;
            f32x2 arg01 = alpha2 * g2[2*qd]   + c2[2*qd];     // pk_fma
            f32x2 arg23 = alpha2 * g2[2*qd+1] + c2[2*qd+1];   // pk_fma
            f32x2 A01, A23;
            A01.x = __builtin_amdgcn_exp2f(arg01.x);
            A01.y = __builtin_amdgcn_exp2f(arg01.y);
            A23.x = __builtin_amdgcn_exp2f(arg23.x);
            A23.y = __builtin_amdgcn_exp2f(arg23.y);
            A01 += (f32x2){1.0f, 1.0f};                       // pk_add
            A23 += (f32x2){1.0f, 1.0f};                       // pk_add
            float P01 = A01.x * A01.y;
            float P23 = A23.x * A23.y;
            float n01 = fmaf(w[b+0], A01.y, w[b+1] * A01.x);
            float n23 = fmaf(w[b+2], A23.y, w[b+3] * A23.x);
            float num = fmaf(n01, P23, n23 * P01);
            float den = P01 * P23;
            p = fmaf(num, __builtin_amdgcn_rcpf(den), p);
        }
        p = row16_allreduce(p);
        float v = __builtin_amdgcn_rcpf(
            __builtin_amdgcn_exp2f(fmaf(-2.0f * K2LE, p, C0)) + 1.0f);
        alpha += fmaf(-0.1f, v, 0.1f);
    }

    // ---- Phase 4: out = pivot + sigmoid(s)*alpha*(r*inv).  Dirs re-loaded
    //      from r (bit-identical values; r is unmodified and L2/L3-hot) ----
    const float sc = sigmoid_fast(sv) * alpha * inv;
    float4 u0 = *(const float4*)&r[ray_g * DIM + m * 8];
    float4 u1 = *(const float4*)&r[ray_g * DIM + m * 8 + 4];
    float4 pv0 = *(const float4*)(pivot + m * 8);
    float4 pv1 = *(const float4*)(pivot + m * 8 + 4);
    float4 o0, o1;
    o0.x = fmaf(sc, u0.x, pv0.x);
    o0.y = fmaf(sc, u0.y, pv0.y);
    o0.z = fmaf(sc, u0.z, pv0.z);
    o0.w = fmaf(sc, u0.w, pv0.w);
    o1.x = fmaf(sc, u1.x, pv1.x);
    o1.y = fmaf(sc, u1.y, pv1.y);
    o1.z = fmaf(sc, u1.z, pv1.z);
    o1.w = fmaf(sc, u1.w, pv1.w);
    *(float4*)(out + ray_g * DIM + m * 8)     = o0;
    *(float4*)(out + ray_g * DIM + m * 8 + 4) = o1;
}

extern "C" void kernel_launch(void* const* d_in, const int* in_sizes, int n_in,
                              void* d_out, int out_size, void* d_ws, size_t ws_size,
                              hipStream_t stream) {
    const float* r      = (const float*)d_in[0];
    const float* s      = (const float*)d_in[1];
    const float* pivot  = (const float*)d_in[2];
    const float* W1     = (const float*)d_in[3];
    const float* b1     = (const float*)d_in[4];
    const float* w2     = (const float*)d_in[5];
    const float* b2     = (const float*)d_in[6];
    const int*   n_iter = (const int*)d_in[7];
    float* out = (float*)d_out;

    const int B = in_sizes[0] / DIM;  // 32768

    char* ws = (char*)d_ws;
    float* c2p = (float*)(ws);             // 1 KB
    float* w2p = (float*)(ws + 1024);      // 1 KB
    uint4* W1f = (uint4*)(ws + 4096);      // 64 KB

    k_prep<<<16, 256, 0, stream>>>(pivot, W1, b1, w2, c2p, w2p, W1f);
    k_main<<<B / 16, 256, 0, stream>>>(r, s, pivot, c2p, w2p, b2, n_iter,
                                       W1f, out);
}

// Round 5
// 120.387 us; speedup vs baseline: 1.0460x; 1.0044x over previous
//
#include <hip/hip_runtime.h>

// Problem constants
#define DIM 128
#define HID 256
#define K2LE 2.885390081777927f   // 2*log2(e): tanh(x) = 1 - 2/(exp2(K2LE*x)+1)
#define NTILES 16                 // HID / 16
#define RNPAD 120                 // rnbf row stride (bf16): 240B = 15*16B, rows 16B-aligned
#define GXPAD 260                 // g_x row stride (f32)

typedef __attribute__((ext_vector_type(8))) short bf16x8;   // 8 bf16 = 4 VGPRs
typedef __attribute__((ext_vector_type(4))) float f32x4;
typedef __attribute__((ext_vector_type(2))) float f32x2;    // -> v_pk_* f32

__device__ __forceinline__ unsigned short f2bf(float f) {
    union { float f; unsigned u; } x; x.f = f;
    unsigned r = x.u + 0x7fffu + ((x.u >> 16) & 1u);   // RNE
    return (unsigned short)(r >> 16);
}

__device__ __forceinline__ float sigmoid_fast(float x) {
    float t = __builtin_amdgcn_exp2f(-x * 1.4426950408889634f);
    return __builtin_amdgcn_rcpf(1.0f + t);
}

// All-reduce sum across a 16-lane DPP row — VALU pipe only, no LDS.
__device__ __forceinline__ float row16_allreduce(float x) {
    int t;
    t = __builtin_amdgcn_update_dpp(0, __float_as_int(x), 0xB1, 0xf, 0xf, true);
    x += __int_as_float(t);
    t = __builtin_amdgcn_update_dpp(0, __float_as_int(x), 0x4E, 0xf, 0xf, true);
    x += __int_as_float(t);
    t = __builtin_amdgcn_update_dpp(0, __float_as_int(x), 0x124, 0xf, 0xf, true);
    x += __int_as_float(t);
    t = __builtin_amdgcn_update_dpp(0, __float_as_int(x), 0x128, 0xf, 0xf, true);
    x += __int_as_float(t);
    return x;
}

// ---------------------------------------------------------------------------
// Prep (16 blocks x 256):
//   block 0: c2p/w2p[(col&15)*16 + (col>>4)] = K2LE*(pivot@W1+b1)[col], w2[col]
//   all:     W1f = bf16(K2LE*W1) in MFMA B-frag order
// ---------------------------------------------------------------------------
__global__ void k_prep(const float* __restrict__ pivot,
                       const float* __restrict__ W1,
                       const float* __restrict__ b1,
                       const float* __restrict__ w2,
                       float* __restrict__ c2p,
                       float* __restrict__ w2p,
                       uint4* __restrict__ W1f) {
    const int tid = threadIdx.x;
    if (blockIdx.x == 0) {
        float a = b1[tid];
#pragma unroll 8
        for (int d = 0; d < DIM; ++d) a = fmaf(pivot[d], W1[d * HID + tid], a);
        const int pidx = (tid & 15) * 16 + (tid >> 4);   // col -> [m][i]
        c2p[pidx] = K2LE * a;
        w2p[pidx] = w2[tid];
    }
    const int e  = blockIdx.x * 256 + tid;
    const int m  = e & 15;
    const int q  = (e >> 4) & 3;
    const int kk = (e >> 6) & 3;
    const int nt = e >> 8;
    const int n  = nt * 16 + m;
    const int k0 = kk * 32 + q * 8;
    unsigned w[4];
#pragma unroll
    for (int p = 0; p < 4; ++p) {
        unsigned lo = f2bf(W1[(k0 + 2 * p    ) * HID + n] * K2LE);
        unsigned hi = f2bf(W1[(k0 + 2 * p + 1) * HID + n] * K2LE);
        w[p] = lo | (hi << 16);
    }
    W1f[e] = make_uint4(w[0], w[1], w[2], w[3]);
}

// ---------------------------------------------------------------------------
// Fused main: 2048 blocks x 256 thr, 16 rays/block.  (exact R4 structure)
//  R16: post-barrier WAVE DESYNC only.  Evidence R0-R4: busy-time (~28us)
//  and dur (~45.5us) invariant to occupancy 36->48% and 7->8 blocks/CU.
//  Model: per iter a wave issues a 16-exp2 trans burst then a VALU section;
//  all waves are phase-locked (identical stream, simultaneous start), so
//  trans and VALU pipes ALTERNATE chip-wide instead of overlapping ->
//  time ~ sum(trans,valu) not max.  Fix: skew waves by (bid^wave)&3 *
//  ~192cyc via s_sleep AFTER the last barrier (march has no barriers, so
//  waves never re-lock).  Wave-uniform branch, zero footprint change.
//  R1/R2 lesson: guard codegen — expect VGPR~36, WRITE_SIZE=16384KB.
// ---------------------------------------------------------------------------
__global__ __launch_bounds__(256, 7) void k_main(
    const float* __restrict__ r,      // [B,128]
    const float* __restrict__ s,      // [B]
    const float* __restrict__ pivot,  // [128]
    const float* __restrict__ c2p,    // [256] permuted K2LE*(pivot@W1+b1)
    const float* __restrict__ w2p,    // [256] permuted w2
    const float* __restrict__ b2,     // [1]
    const int* __restrict__ n_iter_p, // [1]
    const uint4* __restrict__ W1f,    // frag-ordered bf16 K2LE*W1
    float* __restrict__ out)          // [B,128]
{
    __shared__ unsigned short rnbf[16][RNPAD];  // 3.75 KB [ray][k] bf16, padded
    __shared__ float g_x[16][GXPAD];            // 16.25 KB [ray][col] f32, padded

    const int tid   = threadIdx.x;
    const int lane  = tid & 63;
    const int wave  = tid >> 6;        // 0..3: nt-group AND ray-group
    const int m     = lane & 15;
    const int q     = lane >> 4;
    const int ray_l = wave * 4 + q;    // this lane's ray (phases 1,3,4)
    const int ray_g = blockIdx.x * 16 + ray_l;
    const int n_iter = *n_iter_p;

    // ---- Phase 1: load r; bf16 copy to LDS for MFMA; dirs NOT kept live ----
    float4 v0 = *(const float4*)&r[ray_g * DIM + m * 8];
    float4 v1 = *(const float4*)&r[ray_g * DIM + m * 8 + 4];
    const float sv  = s[ray_g];
    const float b2v = b2[0];

    float ss = v0.x*v0.x + v0.y*v0.y + v0.z*v0.z + v0.w*v0.w
             + v1.x*v1.x + v1.y*v1.y + v1.z*v1.z + v1.w*v1.w;
    ss = row16_allreduce(ss);
    const float inv = __builtin_amdgcn_rsqf(ss);
    unsigned p0 = (unsigned)f2bf(v0.x*inv) | ((unsigned)f2bf(v0.y*inv) << 16);
    unsigned p1 = (unsigned)f2bf(v0.z*inv) | ((unsigned)f2bf(v0.w*inv) << 16);
    unsigned p2 = (unsigned)f2bf(v1.x*inv) | ((unsigned)f2bf(v1.y*inv) << 16);
    unsigned p3 = (unsigned)f2bf(v1.z*inv) | ((unsigned)f2bf(v1.w*inv) << 16);
    *(uint4*)&rnbf[ray_l][m * 8] = make_uint4(p0, p1, p2, p3);
    __syncthreads();

    // ---- Phase 2: wave w computes nt = 4w..4w+3 for all 16 rays ----
    bf16x8 afrag[4];
#pragma unroll
    for (int kk = 0; kk < 4; ++kk)
        afrag[kk] = *(const bf16x8*)&rnbf[m][kk * 32 + q * 8];

    const bf16x8* __restrict__ wf = (const bf16x8*)W1f;
    const int fb = q * 16 + m;
#pragma unroll
    for (int t = 0; t < 4; ++t) {
        const int nt = wave * 4 + t;
        f32x4 a = {0.f, 0.f, 0.f, 0.f};
#pragma unroll
        for (int kk = 0; kk < 4; ++kk)
            a = __builtin_amdgcn_mfma_f32_16x16x32_bf16(
                    afrag[kk], wf[nt * 256 + kk * 64 + fb], a, 0, 0, 0);
        // D: row(ray) = q*4+reg, col = nt*16+m  (m89-verified layout)
#pragma unroll
        for (int r4 = 0; r4 < 4; ++r4)
            g_x[q * 4 + r4][nt * 16 + m] = a[r4];
    }
    __syncthreads();

    // ---- Phase 3 setup: lane's 16 cols {i*16+m}, packed into f32x2 pairs ----
    f32x2 g2[8], c2[8];
    float w[16];
#pragma unroll
    for (int j = 0; j < 8; ++j) {
        g2[j].x = g_x[ray_l][(2 * j    ) * 16 + m];
        g2[j].y = g_x[ray_l][(2 * j + 1) * 16 + m];
    }
#pragma unroll
    for (int i = 0; i < 4; ++i) {
        float4 cv = *(const float4*)(c2p + m * 16 + i * 4);
        float4 wv = *(const float4*)(w2p + m * 16 + i * 4);
        c2[2*i]   = (f32x2){cv.x, cv.y};
        c2[2*i+1] = (f32x2){cv.z, cv.w};
        w[4*i]=wv.x; w[4*i+1]=wv.y; w[4*i+2]=wv.z; w[4*i+3]=wv.w;
    }

    float S = 0.f;
#pragma unroll
    for (int i = 0; i < 16; ++i) S += w[i];
    S = row16_allreduce(S);
    const float C0 = K2LE * (S + b2v);

    // ---- R16 desync: stagger waves across ~one march-iteration so the
    //      16-exp2 trans bursts of some waves overlap the VALU sections of
    //      others.  No barrier follows, so the skew persists.  Wave-uniform
    //      condition -> scalar branch, no divergence. ----
    {
        const unsigned sk = (blockIdx.x ^ (unsigned)wave) & 3u;
        if (sk == 1u)      __builtin_amdgcn_s_sleep(3);   // ~192 cyc
        else if (sk == 2u) __builtin_amdgcn_s_sleep(6);   // ~384 cyc
        else if (sk == 3u) __builtin_amdgcn_s_sleep(9);   // ~576 cyc
    }

    // ---- Phase 3: march. Quad-rcp + packed args: one v_rcp per 4 sigmoids,
    //      arg compute and +1.0 as f32x2 (v_pk_fma_f32 / v_pk_add_f32). ----
    float alpha = 0.f;
    for (int it = 0; it < n_iter; ++it) {
        const f32x2 alpha2 = {alpha, alpha};
        float p = 0.f;
#pragma unroll
        for (int qd = 0; qd < 4; ++qd) {
            const int b = qd * 4;
            f32x2 arg01 = alpha2 * g2[2*qd]   + c2[2*qd];     // pk_fma
            f32x2 arg23 = alpha2 * g2[2*qd+1] + c2[2*qd+1];   // pk_fma
            f32x2 A01, A23;
            A01.x = __builtin_amdgcn_exp2f(arg01.x);
            A01.y = __builtin_amdgcn_exp2f(arg01.y);
            A23.x = __builtin_amdgcn_exp2f(arg23.x);
            A23.y = __builtin_amdgcn_exp2f(arg23.y);
            A01 += (f32x2){1.0f, 1.0f};                       // pk_add
            A23 += (f32x2){1.0f, 1.0f};                       // pk_add
            float P01 = A01.x * A01.y;
            float P23 = A23.x * A23.y;
            float n01 = fmaf(w[b+0], A01.y, w[b+1] * A01.x);
            float n23 = fmaf(w[b+2], A23.y, w[b+3] * A23.x);
            float num = fmaf(n01, P23, n23 * P01);
            float den = P01 * P23;
            p = fmaf(num, __builtin_amdgcn_rcpf(den), p);
        }
        p = row16_allreduce(p);
        float v = __builtin_amdgcn_rcpf(
            __builtin_amdgcn_exp2f(fmaf(-2.0f * K2LE, p, C0)) + 1.0f);
        alpha += fmaf(-0.1f, v, 0.1f);
    }

    // ---- Phase 4: out = pivot + sigmoid(s)*alpha*(r*inv).  Dirs re-loaded
    //      from r (bit-identical values; r is unmodified and L2/L3-hot) ----
    const float sc = sigmoid_fast(sv) * alpha * inv;
    float4 u0 = *(const float4*)&r[ray_g * DIM + m * 8];
    float4 u1 = *(const float4*)&r[ray_g * DIM + m * 8 + 4];
    float4 pv0 = *(const float4*)(pivot + m * 8);
    float4 pv1 = *(const float4*)(pivot + m * 8 + 4);
    float4 o0, o1;
    o0.x = fmaf(sc, u0.x, pv0.x);
    o0.y = fmaf(sc, u0.y, pv0.y);
    o0.z = fmaf(sc, u0.z, pv0.z);
    o0.w = fmaf(sc, u0.w, pv0.w);
    o1.x = fmaf(sc, u1.x, pv1.x);
    o1.y = fmaf(sc, u1.y, pv1.y);
    o1.z = fmaf(sc, u1.z, pv1.z);
    o1.w = fmaf(sc, u1.w, pv1.w);
    *(float4*)(out + ray_g * DIM + m * 8)     = o0;
    *(float4*)(out + ray_g * DIM + m * 8 + 4) = o1;
}

extern "C" void kernel_launch(void* const* d_in, const int* in_sizes, int n_in,
                              void* d_out, int out_size, void* d_ws, size_t ws_size,
                              hipStream_t stream) {
    const float* r      = (const float*)d_in[0];
    const float* s      = (const float*)d_in[1];
    const float* pivot  = (const float*)d_in[2];
    const float* W1     = (const float*)d_in[3];
    const float* b1     = (const float*)d_in[4];
    const float* w2     = (const float*)d_in[5];
    const float* b2     = (const float*)d_in[6];
    const int*   n_iter = (const int*)d_in[7];
    float* out = (float*)d_out;

    const int B = in_sizes[0] / DIM;  // 32768

    char* ws = (char*)d_ws;
    float* c2p = (float*)(ws);             // 1 KB
    float* w2p = (float*)(ws + 1024);      // 1 KB
    uint4* W1f = (uint4*)(ws + 4096);      // 64 KB

    k_prep<<<16, 256, 0, stream>>>(pivot, W1, b1, w2, c2p, w2p, W1f);
    k_main<<<B / 16, 256, 0, stream>>>(r, s, pivot, c2p, w2p, b2, n_iter,
                                       W1f, out);
}

// Round 6
// 117.754 us; speedup vs baseline: 1.0694x; 1.0224x over previous
//
#include <hip/hip_runtime.h>

// Problem constants
#define DIM 128
#define HID 256
#define K2LE 2.885390081777927f   // 2*log2(e): tanh(x) = 1 - 2/(exp2(K2LE*x)+1)
#define NTILES 16                 // HID / 16
#define RNPAD 120                 // rnbf row stride (bf16): 240B = 15*16B, rows 16B-aligned
#define GXPAD 260                 // g_x row stride (f32)

typedef __attribute__((ext_vector_type(8))) short bf16x8;   // 8 bf16 = 4 VGPRs
typedef __attribute__((ext_vector_type(4))) float f32x4;
typedef __attribute__((ext_vector_type(2))) float f32x2;    // -> v_pk_* f32

__device__ __forceinline__ unsigned short f2bf(float f) {
    union { float f; unsigned u; } x; x.f = f;
    unsigned r = x.u + 0x7fffu + ((x.u >> 16) & 1u);   // RNE
    return (unsigned short)(r >> 16);
}

__device__ __forceinline__ float sigmoid_fast(float x) {
    float t = __builtin_amdgcn_exp2f(-x * 1.4426950408889634f);
    return __builtin_amdgcn_rcpf(1.0f + t);
}

// All-reduce sum across a 16-lane DPP row — VALU pipe only, no LDS.
__device__ __forceinline__ float row16_allreduce(float x) {
    int t;
    t = __builtin_amdgcn_update_dpp(0, __float_as_int(x), 0xB1, 0xf, 0xf, true);
    x += __int_as_float(t);
    t = __builtin_amdgcn_update_dpp(0, __float_as_int(x), 0x4E, 0xf, 0xf, true);
    x += __int_as_float(t);
    t = __builtin_amdgcn_update_dpp(0, __float_as_int(x), 0x124, 0xf, 0xf, true);
    x += __int_as_float(t);
    t = __builtin_amdgcn_update_dpp(0, __float_as_int(x), 0x128, 0xf, 0xf, true);
    x += __int_as_float(t);
    return x;
}

// ---------------------------------------------------------------------------
// Prep (16 blocks x 256):
//   block 0: c2p/w2p[(col&15)*16 + (col>>4)] = K2LE*(pivot@W1+b1)[col], w2[col]
//   all:     W1f = bf16(K2LE*W1) in MFMA B-frag order
// ---------------------------------------------------------------------------
__global__ void k_prep(const float* __restrict__ pivot,
                       const float* __restrict__ W1,
                       const float* __restrict__ b1,
                       const float* __restrict__ w2,
                       float* __restrict__ c2p,
                       float* __restrict__ w2p,
                       uint4* __restrict__ W1f) {
    const int tid = threadIdx.x;
    if (blockIdx.x == 0) {
        float a = b1[tid];
#pragma unroll 8
        for (int d = 0; d < DIM; ++d) a = fmaf(pivot[d], W1[d * HID + tid], a);
        const int pidx = (tid & 15) * 16 + (tid >> 4);   // col -> [m][i]
        c2p[pidx] = K2LE * a;
        w2p[pidx] = w2[tid];
    }
    const int e  = blockIdx.x * 256 + tid;
    const int m  = e & 15;
    const int q  = (e >> 4) & 3;
    const int kk = (e >> 6) & 3;
    const int nt = e >> 8;
    const int n  = nt * 16 + m;
    const int k0 = kk * 32 + q * 8;
    unsigned w[4];
#pragma unroll
    for (int p = 0; p < 4; ++p) {
        unsigned lo = f2bf(W1[(k0 + 2 * p    ) * HID + n] * K2LE);
        unsigned hi = f2bf(W1[(k0 + 2 * p + 1) * HID + n] * K2LE);
        w[p] = lo | (hi << 16);
    }
    W1f[e] = make_uint4(w[0], w[1], w[2], w[3]);
}

// ---------------------------------------------------------------------------
// Fused main: 2048 blocks x 256 thr, 16 rays/block.  (R4 structure, repacked)
//  R17: FULL v_pk_f32 packing of the march combine tree.  Evidence R0-R5:
//  issue-bound (busy 28.6us invariant to occupancy/desync; ~429cyc/wave-iter
//  fits 68 VALU x2cyc + 22 trans x ~13cyc issue-serial).  Trans count is
//  algorithm-minimal; VALU is not.  Columns re-paired (i, i+4) within each
//  8-col block so BOTH quad-groups sit in lanes .x/.y of the same f32x2:
//  P01/P23/n01/n23/num/den/p all become pk ops.  VALU/iter 68 -> 49.
//  Per-column math identical (p-summation order changes: (q0+q2)+(q1+q3)).
//  Desync removed (R5: null).  Codegen guard: VGPR~36, WRITE=16384KB.
// ---------------------------------------------------------------------------
__global__ __launch_bounds__(256, 7) void k_main(
    const float* __restrict__ r,      // [B,128]
    const float* __restrict__ s,      // [B]
    const float* __restrict__ pivot,  // [128]
    const float* __restrict__ c2p,    // [256] permuted K2LE*(pivot@W1+b1)
    const float* __restrict__ w2p,    // [256] permuted w2
    const float* __restrict__ b2,     // [1]
    const int* __restrict__ n_iter_p, // [1]
    const uint4* __restrict__ W1f,    // frag-ordered bf16 K2LE*W1
    float* __restrict__ out)          // [B,128]
{
    __shared__ unsigned short rnbf[16][RNPAD];  // 3.75 KB [ray][k] bf16, padded
    __shared__ float g_x[16][GXPAD];            // 16.25 KB [ray][col] f32, padded

    const int tid   = threadIdx.x;
    const int lane  = tid & 63;
    const int wave  = tid >> 6;        // 0..3: nt-group AND ray-group
    const int m     = lane & 15;
    const int q     = lane >> 4;
    const int ray_l = wave * 4 + q;    // this lane's ray (phases 1,3,4)
    const int ray_g = blockIdx.x * 16 + ray_l;
    const int n_iter = *n_iter_p;

    // ---- Phase 1: load r; bf16 copy to LDS for MFMA; dirs NOT kept live ----
    float4 v0 = *(const float4*)&r[ray_g * DIM + m * 8];
    float4 v1 = *(const float4*)&r[ray_g * DIM + m * 8 + 4];
    const float sv  = s[ray_g];
    const float b2v = b2[0];

    float ss = v0.x*v0.x + v0.y*v0.y + v0.z*v0.z + v0.w*v0.w
             + v1.x*v1.x + v1.y*v1.y + v1.z*v1.z + v1.w*v1.w;
    ss = row16_allreduce(ss);
    const float inv = __builtin_amdgcn_rsqf(ss);
    unsigned p0 = (unsigned)f2bf(v0.x*inv) | ((unsigned)f2bf(v0.y*inv) << 16);
    unsigned p1 = (unsigned)f2bf(v0.z*inv) | ((unsigned)f2bf(v0.w*inv) << 16);
    unsigned p2 = (unsigned)f2bf(v1.x*inv) | ((unsigned)f2bf(v1.y*inv) << 16);
    unsigned p3 = (unsigned)f2bf(v1.z*inv) | ((unsigned)f2bf(v1.w*inv) << 16);
    *(uint4*)&rnbf[ray_l][m * 8] = make_uint4(p0, p1, p2, p3);
    __syncthreads();

    // ---- Phase 2: wave w computes nt = 4w..4w+3 for all 16 rays ----
    bf16x8 afrag[4];
#pragma unroll
    for (int kk = 0; kk < 4; ++kk)
        afrag[kk] = *(const bf16x8*)&rnbf[m][kk * 32 + q * 8];

    const bf16x8* __restrict__ wf = (const bf16x8*)W1f;
    const int fb = q * 16 + m;
#pragma unroll
    for (int t = 0; t < 4; ++t) {
        const int nt = wave * 4 + t;
        f32x4 a = {0.f, 0.f, 0.f, 0.f};
#pragma unroll
        for (int kk = 0; kk < 4; ++kk)
            a = __builtin_amdgcn_mfma_f32_16x16x32_bf16(
                    afrag[kk], wf[nt * 256 + kk * 64 + fb], a, 0, 0, 0);
        // D: row(ray) = q*4+reg, col = nt*16+m  (m89-verified layout)
#pragma unroll
        for (int r4 = 0; r4 < 4; ++r4)
            g_x[q * 4 + r4][nt * 16 + m] = a[r4];
    }
    __syncthreads();

    // ---- Phase 3 setup: lane's 16 cols {i*16+m}, re-paired (i, i+4) within
    //      each 8-col block P so both quad-groups live in .x/.y lanes. ----
    f32x2 ga[2][4], ca[2][4], wa[2][4];
#pragma unroll
    for (int P = 0; P < 2; ++P)
#pragma unroll
        for (int v = 0; v < 4; ++v) {
            const int ilo = P * 8 + v;
            ga[P][v].x = g_x[ray_l][ ilo      * 16 + m];
            ga[P][v].y = g_x[ray_l][(ilo + 4) * 16 + m];
        }
    {
        float4 cv0 = *(const float4*)(c2p + m * 16);
        float4 cv1 = *(const float4*)(c2p + m * 16 + 4);
        float4 cv2 = *(const float4*)(c2p + m * 16 + 8);
        float4 cv3 = *(const float4*)(c2p + m * 16 + 12);
        ca[0][0] = (f32x2){cv0.x, cv1.x}; ca[0][1] = (f32x2){cv0.y, cv1.y};
        ca[0][2] = (f32x2){cv0.z, cv1.z}; ca[0][3] = (f32x2){cv0.w, cv1.w};
        ca[1][0] = (f32x2){cv2.x, cv3.x}; ca[1][1] = (f32x2){cv2.y, cv3.y};
        ca[1][2] = (f32x2){cv2.z, cv3.z}; ca[1][3] = (f32x2){cv2.w, cv3.w};
        float4 wv0 = *(const float4*)(w2p + m * 16);
        float4 wv1 = *(const float4*)(w2p + m * 16 + 4);
        float4 wv2 = *(const float4*)(w2p + m * 16 + 8);
        float4 wv3 = *(const float4*)(w2p + m * 16 + 12);
        wa[0][0] = (f32x2){wv0.x, wv1.x}; wa[0][1] = (f32x2){wv0.y, wv1.y};
        wa[0][2] = (f32x2){wv0.z, wv1.z}; wa[0][3] = (f32x2){wv0.w, wv1.w};
        wa[1][0] = (f32x2){wv2.x, wv3.x}; wa[1][1] = (f32x2){wv2.y, wv3.y};
        wa[1][2] = (f32x2){wv2.z, wv3.z}; wa[1][3] = (f32x2){wv2.w, wv3.w};
    }

    f32x2 Sv = wa[0][0] + wa[0][1] + wa[0][2] + wa[0][3]
             + wa[1][0] + wa[1][1] + wa[1][2] + wa[1][3];
    float S = Sv.x + Sv.y;
    S = row16_allreduce(S);
    const float C0 = K2LE * (S + b2v);

    // ---- Phase 3: march.  Fully packed combine: per 8-col block P, the two
    //      quad-groups occupy .x/.y of every vector -> pk_mul/pk_fma for
    //      P01/P23/n01/n23/num/den/p.  4 scalar rcp + 16 scalar exp2 remain
    //      (algorithm-minimal trans). ----
    float alpha = 0.f;
    for (int it = 0; it < n_iter; ++it) {
        const f32x2 alpha2 = {alpha, alpha};
        f32x2 p2 = {0.f, 0.f};
#pragma unroll
        for (int P = 0; P < 2; ++P) {
            f32x2 A0 = alpha2 * ga[P][0] + ca[P][0];          // pk_fma
            f32x2 A1 = alpha2 * ga[P][1] + ca[P][1];
            f32x2 A2 = alpha2 * ga[P][2] + ca[P][2];
            f32x2 A3 = alpha2 * ga[P][3] + ca[P][3];
            A0.x = __builtin_amdgcn_exp2f(A0.x); A0.y = __builtin_amdgcn_exp2f(A0.y);
            A1.x = __builtin_amdgcn_exp2f(A1.x); A1.y = __builtin_amdgcn_exp2f(A1.y);
            A2.x = __builtin_amdgcn_exp2f(A2.x); A2.y = __builtin_amdgcn_exp2f(A2.y);
            A3.x = __builtin_amdgcn_exp2f(A3.x); A3.y = __builtin_amdgcn_exp2f(A3.y);
            const f32x2 one = {1.0f, 1.0f};
            A0 += one; A1 += one; A2 += one; A3 += one;       // pk_add
            f32x2 P01 = A0 * A1;                              // pk_mul
            f32x2 P23 = A2 * A3;
            f32x2 n01 = wa[P][0] * A1 + wa[P][1] * A0;        // pk_mul+pk_fma
            f32x2 n23 = wa[P][2] * A3 + wa[P][3] * A2;
            f32x2 num = n01 * P23 + n23 * P01;                // pk_mul+pk_fma
            f32x2 den = P01 * P23;                            // pk_mul
            f32x2 iv;
            iv.x = __builtin_amdgcn_rcpf(den.x);
            iv.y = __builtin_amdgcn_rcpf(den.y);
            p2 = num * iv + p2;                               // pk_fma
        }
        float p = p2.x + p2.y;
        p = row16_allreduce(p);
        float v = __builtin_amdgcn_rcpf(
            __builtin_amdgcn_exp2f(fmaf(-2.0f * K2LE, p, C0)) + 1.0f);
        alpha += fmaf(-0.1f, v, 0.1f);
    }

    // ---- Phase 4: out = pivot + sigmoid(s)*alpha*(r*inv).  Dirs re-loaded
    //      from r (bit-identical values; r is unmodified and L2/L3-hot) ----
    const float sc = sigmoid_fast(sv) * alpha * inv;
    float4 u0 = *(const float4*)&r[ray_g * DIM + m * 8];
    float4 u1 = *(const float4*)&r[ray_g * DIM + m * 8 + 4];
    float4 pv0 = *(const float4*)(pivot + m * 8);
    float4 pv1 = *(const float4*)(pivot + m * 8 + 4);
    float4 o0, o1;
    o0.x = fmaf(sc, u0.x, pv0.x);
    o0.y = fmaf(sc, u0.y, pv0.y);
    o0.z = fmaf(sc, u0.z, pv0.z);
    o0.w = fmaf(sc, u0.w, pv0.w);
    o1.x = fmaf(sc, u1.x, pv1.x);
    o1.y = fmaf(sc, u1.y, pv1.y);
    o1.z = fmaf(sc, u1.z, pv1.z);
    o1.w = fmaf(sc, u1.w, pv1.w);
    *(float4*)(out + ray_g * DIM + m * 8)     = o0;
    *(float4*)(out + ray_g * DIM + m * 8 + 4) = o1;
}

extern "C" void kernel_launch(void* const* d_in, const int* in_sizes, int n_in,
                              void* d_out, int out_size, void* d_ws, size_t ws_size,
                              hipStream_t stream) {
    const float* r      = (const float*)d_in[0];
    const float* s      = (const float*)d_in[1];
    const float* pivot  = (const float*)d_in[2];
    const float* W1     = (const float*)d_in[3];
    const float* b1     = (const float*)d_in[4];
    const float* w2     = (const float*)d_in[5];
    const float* b2     = (const float*)d_in[6];
    const int*   n_iter = (const int*)d_in[7];
    float* out = (float*)d_out;

    const int B = in_sizes[0] / DIM;  // 32768

    char* ws = (char*)d_ws;
    float* c2p = (float*)(ws);             // 1 KB
    float* w2p = (float*)(ws + 1024);      // 1 KB
    uint4* W1f = (uint4*)(ws + 4096);      // 64 KB

    k_prep<<<16, 256, 0, stream>>>(pivot, W1, b1, w2, c2p, w2p, W1f);
    k_main<<<B / 16, 256, 0, stream>>>(r, s, pivot, c2p, w2p, b2, n_iter,
                                       W1f, out);
}

// Round 7
// 113.591 us; speedup vs baseline: 1.1086x; 1.0367x over previous
//
#include <hip/hip_runtime.h>

// Problem constants
#define DIM 128
#define HID 256
#define K2LE 2.885390081777927f   // 2*log2(e): tanh(x) = 1 - 2/(exp2(K2LE*x)+1)
#define NTILES 16                 // HID / 16
#define RNPAD 120                 // rnbf row stride (bf16): 240B = 15*16B, rows 16B-aligned
#define GXPAD 260                 // g_x row stride (f32)

typedef __attribute__((ext_vector_type(8))) short bf16x8;   // 8 bf16 = 4 VGPRs
typedef __attribute__((ext_vector_type(4))) float f32x4;
typedef __attribute__((ext_vector_type(2))) float f32x2;    // -> v_pk_* f32

__device__ __forceinline__ unsigned short f2bf(float f) {
    union { float f; unsigned u; } x; x.f = f;
    unsigned r = x.u + 0x7fffu + ((x.u >> 16) & 1u);   // RNE
    return (unsigned short)(r >> 16);
}

__device__ __forceinline__ float sigmoid_fast(float x) {
    float t = __builtin_amdgcn_exp2f(-x * 1.4426950408889634f);
    return __builtin_amdgcn_rcpf(1.0f + t);
}

// All-reduce sum across a 16-lane DPP row — VALU pipe only, no LDS.
__device__ __forceinline__ float row16_allreduce(float x) {
    int t;
    t = __builtin_amdgcn_update_dpp(0, __float_as_int(x), 0xB1, 0xf, 0xf, true);
    x += __int_as_float(t);
    t = __builtin_amdgcn_update_dpp(0, __float_as_int(x), 0x4E, 0xf, 0xf, true);
    x += __int_as_float(t);
    t = __builtin_amdgcn_update_dpp(0, __float_as_int(x), 0x124, 0xf, 0xf, true);
    x += __int_as_float(t);
    t = __builtin_amdgcn_update_dpp(0, __float_as_int(x), 0x128, 0xf, 0xf, true);
    x += __int_as_float(t);
    return x;
}

// ---------------------------------------------------------------------------
// Prep (16 blocks x 256):
//   block 0: c2p/w2p[(col&15)*16 + (col>>4)] = K2LE*(pivot@W1+b1)[col], w2[col]
//   all:     W1f = bf16(K2LE*W1) in MFMA B-frag order
//  R18: block-0 dot product de-serialized.  Old form: unroll 8 over a single
//  FMA chain -> 16 sequential batches of 8 cold-HBM loads (~5us critical
//  path; k_prep's wall IS this one block).  New: 4 independent accumulators,
//  full unroll -> ~all 128 loads in flight at once; chain ~1 batch of
//  latency.  c2p differs only in f32 add order (ulp; absmax unaffected).
//  W1f part was already 1-load-deep (unroll 8 of independent uint4s): fast.
// ---------------------------------------------------------------------------
__global__ void k_prep(const float* __restrict__ pivot,
                       const float* __restrict__ W1,
                       const float* __restrict__ b1,
                       const float* __restrict__ w2,
                       float* __restrict__ c2p,
                       float* __restrict__ w2p,
                       uint4* __restrict__ W1f) {
    const int tid = threadIdx.x;
    if (blockIdx.x == 0) {
        float a0 = 0.f, a1 = 0.f, a2 = 0.f, a3 = 0.f;
#pragma unroll
        for (int d = 0; d < DIM; d += 4) {
            a0 = fmaf(pivot[d    ], W1[(d    ) * HID + tid], a0);
            a1 = fmaf(pivot[d + 1], W1[(d + 1) * HID + tid], a1);
            a2 = fmaf(pivot[d + 2], W1[(d + 2) * HID + tid], a2);
            a3 = fmaf(pivot[d + 3], W1[(d + 3) * HID + tid], a3);
        }
        const float a = b1[tid] + ((a0 + a2) + (a1 + a3));
        const int pidx = (tid & 15) * 16 + (tid >> 4);   // col -> [m][i]
        c2p[pidx] = K2LE * a;
        w2p[pidx] = w2[tid];
    }
    const int e  = blockIdx.x * 256 + tid;
    const int m  = e & 15;
    const int q  = (e >> 4) & 3;
    const int kk = (e >> 6) & 3;
    const int nt = e >> 8;
    const int n  = nt * 16 + m;
    const int k0 = kk * 32 + q * 8;
    unsigned w[4];
#pragma unroll
    for (int p = 0; p < 4; ++p) {
        unsigned lo = f2bf(W1[(k0 + 2 * p    ) * HID + n] * K2LE);
        unsigned hi = f2bf(W1[(k0 + 2 * p + 1) * HID + n] * K2LE);
        w[p] = lo | (hi << 16);
    }
    W1f[e] = make_uint4(w[0], w[1], w[2], w[3]);
}

// ---------------------------------------------------------------------------
// Fused main: 2048 blocks x 256 thr, 16 rays/block.  (R6 source, UNTOUCHED)
//  R17: FULL v_pk_f32 packing of the march combine tree.  Evidence R0-R5:
//  issue-bound (busy ~27us invariant to occupancy/desync).  Columns paired
//  (i, i+4) within each 8-col block so both quad-groups sit in .x/.y of the
//  same f32x2: P01/P23/n01/n23/num/den/p all pk ops.  VALU/iter 68 -> 49.
//  Confirmed -6% (R6).  Trans (16 exp2 + 4 rcp + 2 tail) is algorithm-
//  minimal: 8-wide rcp grouping overflows f32 for |y|>~6.5.
//  DO NOT perturb this kernel's source: entry-region edits flipped codegen
//  into a 32-VGPR spill schedule twice (R1/R2; WRITE 16->45MB signature).
// ---------------------------------------------------------------------------
__global__ __launch_bounds__(256, 7) void k_main(
    const float* __restrict__ r,      // [B,128]
    const float* __restrict__ s,      // [B]
    const float* __restrict__ pivot,  // [128]
    const float* __restrict__ c2p,    // [256] permuted K2LE*(pivot@W1+b1)
    const float* __restrict__ w2p,    // [256] permuted w2
    const float* __restrict__ b2,     // [1]
    const int* __restrict__ n_iter_p, // [1]
    const uint4* __restrict__ W1f,    // frag-ordered bf16 K2LE*W1
    float* __restrict__ out)          // [B,128]
{
    __shared__ unsigned short rnbf[16][RNPAD];  // 3.75 KB [ray][k] bf16, padded
    __shared__ float g_x[16][GXPAD];            // 16.25 KB [ray][col] f32, padded

    const int tid   = threadIdx.x;
    const int lane  = tid & 63;
    const int wave  = tid >> 6;        // 0..3: nt-group AND ray-group
    const int m     = lane & 15;
    const int q     = lane >> 4;
    const int ray_l = wave * 4 + q;    // this lane's ray (phases 1,3,4)
    const int ray_g = blockIdx.x * 16 + ray_l;
    const int n_iter = *n_iter_p;

    // ---- Phase 1: load r; bf16 copy to LDS for MFMA; dirs NOT kept live ----
    float4 v0 = *(const float4*)&r[ray_g * DIM + m * 8];
    float4 v1 = *(const float4*)&r[ray_g * DIM + m * 8 + 4];
    const float sv  = s[ray_g];
    const float b2v = b2[0];

    float ss = v0.x*v0.x + v0.y*v0.y + v0.z*v0.z + v0.w*v0.w
             + v1.x*v1.x + v1.y*v1.y + v1.z*v1.z + v1.w*v1.w;
    ss = row16_allreduce(ss);
    const float inv = __builtin_amdgcn_rsqf(ss);
    unsigned p0 = (unsigned)f2bf(v0.x*inv) | ((unsigned)f2bf(v0.y*inv) << 16);
    unsigned p1 = (unsigned)f2bf(v0.z*inv) | ((unsigned)f2bf(v0.w*inv) << 16);
    unsigned p2 = (unsigned)f2bf(v1.x*inv) | ((unsigned)f2bf(v1.y*inv) << 16);
    unsigned p3 = (unsigned)f2bf(v1.z*inv) | ((unsigned)f2bf(v1.w*inv) << 16);
    *(uint4*)&rnbf[ray_l][m * 8] = make_uint4(p0, p1, p2, p3);
    __syncthreads();

    // ---- Phase 2: wave w computes nt = 4w..4w+3 for all 16 rays ----
    bf16x8 afrag[4];
#pragma unroll
    for (int kk = 0; kk < 4; ++kk)
        afrag[kk] = *(const bf16x8*)&rnbf[m][kk * 32 + q * 8];

    const bf16x8* __restrict__ wf = (const bf16x8*)W1f;
    const int fb = q * 16 + m;
#pragma unroll
    for (int t = 0; t < 4; ++t) {
        const int nt = wave * 4 + t;
        f32x4 a = {0.f, 0.f, 0.f, 0.f};
#pragma unroll
        for (int kk = 0; kk < 4; ++kk)
            a = __builtin_amdgcn_mfma_f32_16x16x32_bf16(
                    afrag[kk], wf[nt * 256 + kk * 64 + fb], a, 0, 0, 0);
        // D: row(ray) = q*4+reg, col = nt*16+m  (m89-verified layout)
#pragma unroll
        for (int r4 = 0; r4 < 4; ++r4)
            g_x[q * 4 + r4][nt * 16 + m] = a[r4];
    }
    __syncthreads();

    // ---- Phase 3 setup: lane's 16 cols {i*16+m}, re-paired (i, i+4) within
    //      each 8-col block P so both quad-groups live in .x/.y lanes. ----
    f32x2 ga[2][4], ca[2][4], wa[2][4];
#pragma unroll
    for (int P = 0; P < 2; ++P)
#pragma unroll
        for (int v = 0; v < 4; ++v) {
            const int ilo = P * 8 + v;
            ga[P][v].x = g_x[ray_l][ ilo      * 16 + m];
            ga[P][v].y = g_x[ray_l][(ilo + 4) * 16 + m];
        }
    {
        float4 cv0 = *(const float4*)(c2p + m * 16);
        float4 cv1 = *(const float4*)(c2p + m * 16 + 4);
        float4 cv2 = *(const float4*)(c2p + m * 16 + 8);
        float4 cv3 = *(const float4*)(c2p + m * 16 + 12);
        ca[0][0] = (f32x2){cv0.x, cv1.x}; ca[0][1] = (f32x2){cv0.y, cv1.y};
        ca[0][2] = (f32x2){cv0.z, cv1.z}; ca[0][3] = (f32x2){cv0.w, cv1.w};
        ca[1][0] = (f32x2){cv2.x, cv3.x}; ca[1][1] = (f32x2){cv2.y, cv3.y};
        ca[1][2] = (f32x2){cv2.z, cv3.z}; ca[1][3] = (f32x2){cv2.w, cv3.w};
        float4 wv0 = *(const float4*)(w2p + m * 16);
        float4 wv1 = *(const float4*)(w2p + m * 16 + 4);
        float4 wv2 = *(const float4*)(w2p + m * 16 + 8);
        float4 wv3 = *(const float4*)(w2p + m * 16 + 12);
        wa[0][0] = (f32x2){wv0.x, wv1.x}; wa[0][1] = (f32x2){wv0.y, wv1.y};
        wa[0][2] = (f32x2){wv0.z, wv1.z}; wa[0][3] = (f32x2){wv0.w, wv1.w};
        wa[1][0] = (f32x2){wv2.x, wv3.x}; wa[1][1] = (f32x2){wv2.y, wv3.y};
        wa[1][2] = (f32x2){wv2.z, wv3.z}; wa[1][3] = (f32x2){wv2.w, wv3.w};
    }

    f32x2 Sv = wa[0][0] + wa[0][1] + wa[0][2] + wa[0][3]
             + wa[1][0] + wa[1][1] + wa[1][2] + wa[1][3];
    float S = Sv.x + Sv.y;
    S = row16_allreduce(S);
    const float C0 = K2LE * (S + b2v);

    // ---- Phase 3: march.  Fully packed combine: per 8-col block P, the two
    //      quad-groups occupy .x/.y of every vector -> pk_mul/pk_fma for
    //      P01/P23/n01/n23/num/den/p.  4 scalar rcp + 16 scalar exp2 remain
    //      (algorithm-minimal trans). ----
    float alpha = 0.f;
    for (int it = 0; it < n_iter; ++it) {
        const f32x2 alpha2 = {alpha, alpha};
        f32x2 p2 = {0.f, 0.f};
#pragma unroll
        for (int P = 0; P < 2; ++P) {
            f32x2 A0 = alpha2 * ga[P][0] + ca[P][0];          // pk_fma
            f32x2 A1 = alpha2 * ga[P][1] + ca[P][1];
            f32x2 A2 = alpha2 * ga[P][2] + ca[P][2];
            f32x2 A3 = alpha2 * ga[P][3] + ca[P][3];
            A0.x = __builtin_amdgcn_exp2f(A0.x); A0.y = __builtin_amdgcn_exp2f(A0.y);
            A1.x = __builtin_amdgcn_exp2f(A1.x); A1.y = __builtin_amdgcn_exp2f(A1.y);
            A2.x = __builtin_amdgcn_exp2f(A2.x); A2.y = __builtin_amdgcn_exp2f(A2.y);
            A3.x = __builtin_amdgcn_exp2f(A3.x); A3.y = __builtin_amdgcn_exp2f(A3.y);
            const f32x2 one = {1.0f, 1.0f};
            A0 += one; A1 += one; A2 += one; A3 += one;       // pk_add
            f32x2 P01 = A0 * A1;                              // pk_mul
            f32x2 P23 = A2 * A3;
            f32x2 n01 = wa[P][0] * A1 + wa[P][1] * A0;        // pk_mul+pk_fma
            f32x2 n23 = wa[P][2] * A3 + wa[P][3] * A2;
            f32x2 num = n01 * P23 + n23 * P01;                // pk_mul+pk_fma
            f32x2 den = P01 * P23;                            // pk_mul
            f32x2 iv;
            iv.x = __builtin_amdgcn_rcpf(den.x);
            iv.y = __builtin_amdgcn_rcpf(den.y);
            p2 = num * iv + p2;                               // pk_fma
        }
        float p = p2.x + p2.y;
        p = row16_allreduce(p);
        float v = __builtin_amdgcn_rcpf(
            __builtin_amdgcn_exp2f(fmaf(-2.0f * K2LE, p, C0)) + 1.0f);
        alpha += fmaf(-0.1f, v, 0.1f);
    }

    // ---- Phase 4: out = pivot + sigmoid(s)*alpha*(r*inv).  Dirs re-loaded
    //      from r (bit-identical values; r is unmodified and L2/L3-hot) ----
    const float sc = sigmoid_fast(sv) * alpha * inv;
    float4 u0 = *(const float4*)&r[ray_g * DIM + m * 8];
    float4 u1 = *(const float4*)&r[ray_g * DIM + m * 8 + 4];
    float4 pv0 = *(const float4*)(pivot + m * 8);
    float4 pv1 = *(const float4*)(pivot + m * 8 + 4);
    float4 o0, o1;
    o0.x = fmaf(sc, u0.x, pv0.x);
    o0.y = fmaf(sc, u0.y, pv0.y);
    o0.z = fmaf(sc, u0.z, pv0.z);
    o0.w = fmaf(sc, u0.w, pv0.w);
    o1.x = fmaf(sc, u1.x, pv1.x);
    o1.y = fmaf(sc, u1.y, pv1.y);
    o1.z = fmaf(sc, u1.z, pv1.z);
    o1.w = fmaf(sc, u1.w, pv1.w);
    *(float4*)(out + ray_g * DIM + m * 8)     = o0;
    *(float4*)(out + ray_g * DIM + m * 8 + 4) = o1;
}

extern "C" void kernel_launch(void* const* d_in, const int* in_sizes, int n_in,
                              void* d_out, int out_size, void* d_ws, size_t ws_size,
                              hipStream_t stream) {
    const float* r      = (const float*)d_in[0];
    const float* s      = (const float*)d_in[1];
    const float* pivot  = (const float*)d_in[2];
    const float* W1     = (const float*)d_in[3];
    const float* b1     = (const float*)d_in[4];
    const float* w2     = (const float*)d_in[5];
    const float* b2     = (const float*)d_in[6];
    const int*   n_iter = (const int*)d_in[7];
    float* out = (float*)d_out;

    const int B = in_sizes[0] / DIM;  // 32768

    char* ws = (char*)d_ws;
    float* c2p = (float*)(ws);             // 1 KB
    float* w2p = (float*)(ws + 1024);      // 1 KB
    uint4* W1f = (uint4*)(ws + 4096);      // 64 KB

    k_prep<<<16, 256, 0, stream>>>(pivot, W1, b1, w2, c2p, w2p, W1f);
    k_main<<<B / 16, 256, 0, stream>>>(r, s, pivot, c2p, w2p, b2, n_iter,
                                       W1f, out);
}